// Round 15
// baseline (102.504 us; speedup 1.0000x reference)
//
#include <hip/hip_runtime.h>
#include <math.h>

#define HIDDEN 1024
#define NL 9
#define LEAN_TAU 0.25f
#define LEAN_DELTA 0.35f
#define LCH 16  // CRF scan chunk length

// v_add_f32 with DPP cross-lane source: full VALU rate, zero DS-pipe traffic.
template <int CTRL>
__device__ __forceinline__ float dppadd(float v) {
  const int s =
      __builtin_amdgcn_update_dpp(0, __float_as_int(v), CTRL, 0xf, 0xf, true);
  return v + __int_as_float(s);
}
// full-wave sum -> lane 63: row_shr 1,2,4,8 then row_bcast15, row_bcast31
__device__ __forceinline__ float wave_sum63(float v) {
  v = dppadd<0x111>(v);
  v = dppadd<0x112>(v);
  v = dppadd<0x114>(v);
  v = dppadd<0x118>(v);
  v = dppadd<0x142>(v);
  v = dppadd<0x143>(v);
  return v;
}

// ---------------- Kernel 1: emission logits + lean adjust (R14 best) --------
__global__ __launch_bounds__(256) void logits_k(
    const float* __restrict__ hs, const float* __restrict__ w,
    const float* __restrict__ bias, const int* __restrict__ amask,
    float* __restrict__ e, int B, int T) {
  __shared__ float lw[NL * HIDDEN];
  const int TOK = T - 2;
  for (int i = threadIdx.x; i < NL * HIDDEN / 4; i += blockDim.x)
    reinterpret_cast<float4*>(lw)[i] = reinterpret_cast<const float4*>(w)[i];
  __syncthreads();
  const int wave = threadIdx.x >> 6, lane = threadIdx.x & 63;
  const int nTok = B * TOK;
  float bb[NL];
#pragma unroll
  for (int l = 0; l < NL; ++l) bb[l] = bias[l];

  const int nW2 = gridDim.x * 4 * 2;
  for (int base = (blockIdx.x * 4 + wave) * 2; base < nTok; base += nW2) {
    const int b0 = base / TOK, t0 = base - b0 * TOK;
    const int b1 = (base + 1) / TOK, t1 = (base + 1) - b1 * TOK;
    const float4* r0 =
        reinterpret_cast<const float4*>(hs + ((size_t)b0 * T + t0 + 1) * HIDDEN);
    const float4* r1 =
        reinterpret_cast<const float4*>(hs + ((size_t)b1 * T + t1 + 1) * HIDDEN);
    float4 hv0[4], hv1[4];
#pragma unroll
    for (int k = 0; k < 4; ++k) {
      hv0[k] = r0[lane + 64 * k];
      hv1[k] = r1[lane + 64 * k];
    }
    const int am0 = amask[b0 * T + t0 + 1];
    const int am1 = amask[b1 * T + t1 + 1];

    float acc0[NL], acc1[NL];
#pragma unroll
    for (int l = 0; l < NL; ++l) acc0[l] = acc1[l] = 0.f;
#pragma unroll
    for (int k = 0; k < 4; ++k) {
      const int h4 = lane + 64 * k;
#pragma unroll
      for (int l = 0; l < NL; ++l) {
        const float4 wv = reinterpret_cast<const float4*>(lw + l * HIDDEN)[h4];
        acc0[l] = fmaf(hv0[k].x, wv.x,
                  fmaf(hv0[k].y, wv.y,
                  fmaf(hv0[k].z, wv.z, fmaf(hv0[k].w, wv.w, acc0[l]))));
        acc1[l] = fmaf(hv1[k].x, wv.x,
                  fmaf(hv1[k].y, wv.y,
                  fmaf(hv1[k].z, wv.z, fmaf(hv1[k].w, wv.w, acc1[l]))));
      }
    }
#pragma unroll
    for (int l = 0; l < NL; ++l) {
      acc0[l] = wave_sum63(acc0[l]) + bb[l];
      acc1[l] = wave_sum63(acc1[l]) + bb[l];
    }
    float m1 = -INFINITY, m2 = -INFINITY, n1 = -INFINITY, n2 = -INFINITY;
#pragma unroll
    for (int l = 0; l < NL; ++l) {
      const float v0 = acc0[l];
      if (v0 > m1) { m2 = m1; m1 = v0; }
      else if (v0 > m2) { m2 = v0; }
      const float v1 = acc1[l];
      if (v1 > n1) { n2 = n1; n1 = v1; }
      else if (v1 > n2) { n2 = v1; }
    }
    if ((m1 - m2 < LEAN_TAU) && (am0 != 0)) acc0[0] += LEAN_DELTA;
    if ((n1 - n2 < LEAN_TAU) && (am1 != 0)) acc1[0] += LEAN_DELTA;
    if (lane == 63) {
      float* d0 = e + (size_t)base * NL;
#pragma unroll
      for (int l = 0; l < NL; ++l) d0[l] = acc0[l];
      float* d1 = e + (size_t)(base + 1) * NL;
#pragma unroll
      for (int l = 0; l < NL; ++l) d1[l] = acc1[l];
    }
  }
}

// ---------------- ABLATION PROBE: pure read-stream of hs --------------------
// Identical addressing to logits_k (4 x float4 per row + amask), 16 dependent
// adds/token, one live store per wave. Measures the true achievable read
// rate for this access pattern in this harness state (V0 = dur - 80.8us).
__global__ __launch_bounds__(256) void stream_k(
    const float* __restrict__ hs, const int* __restrict__ amask,
    float* __restrict__ sink, int B, int T) {
  const int TOK = T - 2, nTok = B * TOK;
  const int lane = threadIdx.x & 63;
  const int wid = blockIdx.x * 4 + (threadIdx.x >> 6);
  const int nW = gridDim.x * 4;
  float acc = 0.f;
  int ai = 0;
  for (int tok = wid; tok < nTok; tok += nW) {
    const int b = tok / TOK, t = tok - b * TOK;
    const float4* row = reinterpret_cast<const float4*>(
        hs + ((size_t)b * T + t + 1) * HIDDEN);
    const float4 h0 = row[lane];
    const float4 h1 = row[lane + 64];
    const float4 h2 = row[lane + 128];
    const float4 h3 = row[lane + 192];
    acc += h0.x + h0.y + h0.z + h0.w;
    acc += h1.x + h1.y + h1.z + h1.w;
    acc += h2.x + h2.y + h2.z + h2.w;
    acc += h3.x + h3.y + h3.z + h3.w;
    ai += amask[b * T + t + 1];
  }
  if (lane == 0) sink[wid] = acc + (float)ai;  // keeps everything live
}

// ---------------- Kernel 2: per-chunk log-space matrix products -------------
__global__ __launch_bounds__(64) void chunk_k(
    const float* __restrict__ e, const int* __restrict__ labels,
    const float* __restrict__ trans, float* __restrict__ Pout,
    int B, int T, int C) {
  const int TOK = T - 2;
  __shared__ float e2[7][LCH][NL];
  __shared__ float tr2[NL * NL];
  __shared__ int msk[7][LCH];
  const int tid = threadIdx.x;
  const int nG = B * C;
  const int gbase = blockIdx.x * 7;

  for (int idx = tid; idx < NL * NL; idx += 64) tr2[idx] = trans[idx];
  for (int idx = tid; idx < 7 * LCH * NL; idx += 64) {
    const int sub = idx / (LCH * NL), rem = idx % (LCH * NL);
    const int step = rem / NL, j = rem % NL;
    const int g = gbase + sub;
    if (g < nG) {
      const int b = g / C, c = g % C;
      const int t = 1 + c * LCH + step;
      if (t < TOK) e2[sub][step][j] = e[((size_t)b * TOK + t) * NL + j];
    }
  }
  for (int idx = tid; idx < 7 * LCH; idx += 64) {
    const int sub = idx / LCH, step = idx % LCH;
    const int g = gbase + sub;
    if (g < nG) {
      const int b = g / C, c = g % C;
      const int t = 1 + c * LCH + step;
      msk[sub][step] = (t < TOK) ? (labels[(size_t)b * T + 1 + t] != -100) : 0;
    }
  }
  __syncthreads();

  const int sub = tid / NL, i = tid % NL;
  const int g = gbase + sub;
  const bool act = (sub < 7) && (g < nG);
  int len = 1;
  if (act) { const int c = g % C; len = min(LCH, TOK - (1 + c * LCH)); }

  float W[NL][NL];
#pragma unroll
  for (int k = 0; k < NL; ++k)
#pragma unroll
    for (int j = 0; j < NL; ++j) W[k][j] = __expf(tr2[k * NL + j]);

  float P[NL];
  {
    const int m0 = act ? msk[sub][0] : 0;
#pragma unroll
    for (int j = 0; j < NL; ++j)
      P[j] = m0 ? (tr2[i * NL + j] + e2[sub][0][j])
                : ((i == j) ? 0.f : -1e30f);
  }
  for (int step = 1; step < len; ++step) {
    const int mt = msk[sub][step];
    float mx = P[0];
#pragma unroll
    for (int k = 1; k < NL; ++k) mx = fmaxf(mx, P[k]);
    float E[NL];
#pragma unroll
    for (int k = 0; k < NL; ++k) E[k] = __expf(P[k] - mx);
    float Pn[NL];
#pragma unroll
    for (int j = 0; j < NL; ++j) {
      float s = 0.f;
#pragma unroll
      for (int k = 0; k < NL; ++k) s = fmaf(E[k], W[k][j], s);
      Pn[j] = mx + __logf(s) + e2[sub][step][j];
    }
#pragma unroll
    for (int j = 0; j < NL; ++j) P[j] = mt ? Pn[j] : P[j];
  }
  if (act) {
    float* dst = Pout + (size_t)g * 81 + i * NL;
#pragma unroll
    for (int j = 0; j < NL; ++j) dst[j] = P[j];
  }
}

// ---------------- Kernel 3: per-batch combine (num + den fold) --------------
__global__ __launch_bounds__(64) void combine_k(
    const float* __restrict__ e, const int* __restrict__ labels,
    const float* __restrict__ start_t, const float* __restrict__ end_t,
    const float* __restrict__ trans, const float* __restrict__ Pmat,
    float* __restrict__ llh, int B, int T, int C) {
  const int TOK = T - 2;
  const int b = blockIdx.x, lane = threadIdx.x;
  const float* eb = e + (size_t)b * TOK * NL;
  const int* lb = labels + (size_t)b * T + 1;

  const int g0r = lb[0];
  const int tg0 = (g0r == -100) ? 0 : g0r;
  float nsum = 0.f;
  int pack = -1;
  for (int t = 1 + lane; t < TOK; t += 64) {
    const int gr = lb[t], pr = lb[t - 1];
    if (gr != -100) {
      const int cur = gr;
      const int prev = (pr == -100) ? 0 : pr;
      nsum += trans[prev * NL + cur] + eb[t * NL + cur];
      pack = (t << 4) | cur;
    }
  }
#pragma unroll
  for (int off = 32; off; off >>= 1) {
    nsum += __shfl_xor(nsum, off);
    pack = max(pack, __shfl_xor(pack, off));
  }
  const int last = (pack < 0) ? tg0 : (pack & 15);
  const float num = start_t[tg0] + eb[tg0] + nsum + end_t[last];

  float alpha = (lane < NL) ? (start_t[lane] + eb[lane]) : -1e30f;
  for (int c = 0; c < C; ++c) {
    const float* Pc = Pmat + ((size_t)b * C + c) * 81;
    float col[NL];
#pragma unroll
    for (int i = 0; i < NL; ++i)
      col[i] = (lane < NL) ? Pc[i * NL + lane] : -1e30f;
    float s[NL];
    float mx = -1e30f;
#pragma unroll
    for (int i = 0; i < NL; ++i) {
      const float ai = __shfl(alpha, i);
      s[i] = ai + col[i];
      mx = fmaxf(mx, s[i]);
    }
    float sum = 0.f;
#pragma unroll
    for (int i = 0; i < NL; ++i) sum += __expf(s[i] - mx);
    const float nx = mx + __logf(sum);
    alpha = (lane < NL) ? nx : -1e30f;
  }
  const float v = (lane < NL) ? (alpha + end_t[lane]) : -1e30f;
  float mx = v;
#pragma unroll
  for (int off = 32; off; off >>= 1) mx = fmaxf(mx, __shfl_xor(mx, off));
  float sum = (lane < NL) ? __expf(v - mx) : 0.f;
#pragma unroll
  for (int off = 32; off; off >>= 1) sum += __shfl_xor(sum, off);
  const float den = mx + __logf(sum);
  if (lane == 0) llh[b] = num - den;
}

// ---------------- Kernel 4: -mean(llh) ----------------
__global__ __launch_bounds__(64) void reduce_k(const float* __restrict__ llh,
                                               float* __restrict__ out, int B) {
  float v = 0.f;
  for (int i = threadIdx.x; i < B; i += 64) v += llh[i];
#pragma unroll
  for (int off = 32; off; off >>= 1) v += __shfl_xor(v, off);
  if (threadIdx.x == 0) out[0] = -v / (float)B;
}

extern "C" void kernel_launch(void* const* d_in, const int* in_sizes, int n_in,
                              void* d_out, int out_size, void* d_ws,
                              size_t ws_size, hipStream_t stream) {
  const float* hs     = (const float*)d_in[0];
  const float* w      = (const float*)d_in[1];
  const float* bias   = (const float*)d_in[2];
  const float* st     = (const float*)d_in[3];
  const float* et     = (const float*)d_in[4];
  const float* tr     = (const float*)d_in[5];
  const int*   amask  = (const int*)d_in[6];
  const int*   labels = (const int*)d_in[7];

  const int T = 512;
  const int B = in_sizes[6] / T;
  const int TOK = T - 2;
  const int C = (TOK - 1 + LCH - 1) / LCH;

  float* e    = (float*)d_ws;                 // (B, TOK, 9)
  float* llh  = e + (size_t)B * TOK * NL;     // (B,)
  float* Pmat = llh + B;                      // (B*C, 81)
  float* sink = (float*)d_ws + 500000;        // probe sink, past live data

  logits_k<<<2048, 256, 0, stream>>>(hs, w, bias, amask, e, B, T);
  const int nG = B * C;
  chunk_k<<<(nG + 6) / 7, 64, 0, stream>>>(e, labels, tr, Pmat, B, T, C);
  combine_k<<<B, 64, 0, stream>>>(e, labels, st, et, tr, Pmat, llh, B, T, C);
  reduce_k<<<1, 64, 0, stream>>>(llh, (float*)d_out, B);
  // ablation probe LAST (inherits the same steady-state L3 as logits_k does)
  stream_k<<<2048, 256, 0, stream>>>(hs, amask, sink, B, T);
}

// Round 16
// 73.363 us; speedup vs baseline: 1.3972x; 1.3972x over previous
//
#include <hip/hip_runtime.h>
#include <math.h>

#define HIDDEN 1024
#define NL 9
#define LEAN_TAU 0.25f
#define LEAN_DELTA 0.35f
#define LCH 16
#define TFIX 512
#define TOKFIX 510  // T-2, compile-time so /TOK compiles to magic-mul

typedef __attribute__((ext_vector_type(8))) short short8v;
typedef __attribute__((ext_vector_type(4))) float f32x4;
typedef __attribute__((ext_vector_type(4))) unsigned uint4v;
union frag_u { uint4v u; short8v s; };

// pack 2 fp32 -> 2 bf16 (truncation; |rel err| <= 2^-8, NLL effect << 24.3)
__device__ __forceinline__ unsigned pk2(float a, float b) {
  return (__float_as_uint(b) & 0xffff0000u) | (__float_as_uint(a) >> 16);
}

// ---------------- Kernel 1: K-split MFMA logits + lean adjust ---------------
// One block = one 16-token tile; wave w owns K-slice [256w,256w+256).
// R15 ablation: identical hs addressing streams at 5.9TB/s when per-token
// work ~20 instrs; scalar variants (~240 instrs/tok) plateau at 2.1TB/s.
// This kernel: ~50 instrs/token, 16 waves/CU, MFMA does the K-reduction.
__global__ __launch_bounds__(256) void mfma_k(
    const float* __restrict__ hs, const float* __restrict__ w,
    const float* __restrict__ bias, const int* __restrict__ amask,
    float* __restrict__ e, int B) {
  const int nTok = B * TOKFIX;
  const int wave = threadIdx.x >> 6, lane = threadIdx.x & 63;
  const int g = lane >> 4, c = lane & 15;
  __shared__ unsigned short aw[4][16][264];  // per-wave bf16 A-slice (+pad)
  __shared__ float4 cp[3][64];               // partial C from waves 1..3

  const int base = blockIdx.x * 16;
  // ---- stage A: 16 rows x 256 f32 -> bf16 LDS; one coalesced 1KB load/row --
  {
    int b = base / TOKFIX, t = base - b * TOKFIX;  // magic-mul (const divisor)
#pragma unroll
    for (int j = 0; j < 16; ++j) {
      const int tok = base + j;
      const float* src =
          hs + ((size_t)b * TFIX + ((tok < nTok) ? t : 0) + 1) * HIDDEN;
      const float4 f =
          *reinterpret_cast<const float4*>(src + wave * 256 + lane * 4);
      uint2 pk;
      pk.x = pk2(f.x, f.y);
      pk.y = pk2(f.z, f.w);
      *reinterpret_cast<uint2*>(&aw[wave][j][lane * 4]) = pk;
      if (++t >= TOKFIX) { t = 0; ++b; }
    }
  }
  // ---- B fragments from global (w is 36KB, L2-hot) ----
  frag_u bfrag[8];
  {
    const int brow = (c < NL) ? c : 0;
    const float* wp = w + (size_t)brow * HIDDEN + wave * 256 + g * 8;
#pragma unroll
    for (int s = 0; s < 8; ++s) {
      const float4 u0 = *reinterpret_cast<const float4*>(wp + s * 32);
      const float4 u1 = *reinterpret_cast<const float4*>(wp + s * 32 + 4);
      unsigned d0 = pk2(u0.x, u0.y), d1 = pk2(u0.z, u0.w);
      unsigned d2 = pk2(u1.x, u1.y), d3 = pk2(u1.z, u1.w);
      if (c >= NL) d0 = d1 = d2 = d3 = 0u;
      bfrag[s].u = uint4v{d0, d1, d2, d3};
    }
  }
  __syncthreads();

  // ---- 8 MFMAs over this wave's K=256 (R10-verified fragment layout) ----
  f32x4 acc = {0.f, 0.f, 0.f, 0.f};
#pragma unroll
  for (int s = 0; s < 8; ++s) {
    const short8v a =
        *reinterpret_cast<const short8v*>(&aw[wave][c][s * 32 + g * 8]);
    acc = __builtin_amdgcn_mfma_f32_16x16x32_bf16(a, bfrag[s].s, acc, 0, 0, 0);
  }

  // ---- cross-wave partial-C reduce ----
  if (wave != 0) cp[wave - 1][lane] = *reinterpret_cast<float4*>(&acc);
  __syncthreads();
  if (wave == 0) {
#pragma unroll
    for (int k = 0; k < 3; ++k) {
      const float4 p = cp[k][lane];
      acc[0] += p.x; acc[1] += p.y; acc[2] += p.z; acc[3] += p.w;
    }
    // ---- epilogue: bias, top-2 (16-lane butterfly), lean, store ----
    const float bc = (c < NL) ? bias[c] : 0.f;
#pragma unroll
    for (int j = 0; j < 4; ++j) {
      const int tok = base + g * 4 + j;  // C/D row = g*4+j, col = c (verified)
      const int tokc = (tok < nTok) ? tok : 0;
      const int b = tokc / TOKFIX, t = tokc - b * TOKFIX;
      const float v = acc[j] + bc;
      float m1 = (c < NL) ? v : -1e30f, m2 = -1e30f;
#pragma unroll
      for (int off = 1; off < 16; off <<= 1) {
        const float om1 = __shfl_xor(m1, off);
        const float om2 = __shfl_xor(m2, off);
        const float hi = fmaxf(m1, om1);
        const float lo = fminf(m1, om1);
        m2 = fmaxf(lo, fmaxf(m2, om2));
        m1 = hi;
      }
      const bool unc = (m1 - m2 < LEAN_TAU) && (amask[b * TFIX + t + 1] != 0);
      const float vout = v + ((unc && c == 0) ? LEAN_DELTA : 0.f);
      if (c < NL && tok < nTok) e[(size_t)tok * NL + c] = vout;
    }
  }
}

// ---------------- Kernel 2: per-chunk log-space matrix products -------------
__global__ __launch_bounds__(64) void chunk_k(
    const float* __restrict__ e, const int* __restrict__ labels,
    const float* __restrict__ trans, float* __restrict__ Pout,
    int B, int T, int C) {
  const int TOK = T - 2;
  __shared__ float e2[7][LCH][NL];
  __shared__ float tr2[NL * NL];
  __shared__ int msk[7][LCH];
  const int tid = threadIdx.x;
  const int nG = B * C;
  const int gbase = blockIdx.x * 7;

  for (int idx = tid; idx < NL * NL; idx += 64) tr2[idx] = trans[idx];
  for (int idx = tid; idx < 7 * LCH * NL; idx += 64) {
    const int sub = idx / (LCH * NL), rem = idx % (LCH * NL);
    const int step = rem / NL, j = rem % NL;
    const int g = gbase + sub;
    if (g < nG) {
      const int b = g / C, c = g % C;
      const int t = 1 + c * LCH + step;
      if (t < TOK) e2[sub][step][j] = e[((size_t)b * TOK + t) * NL + j];
    }
  }
  for (int idx = tid; idx < 7 * LCH; idx += 64) {
    const int sub = idx / LCH, step = idx % LCH;
    const int g = gbase + sub;
    if (g < nG) {
      const int b = g / C, c = g % C;
      const int t = 1 + c * LCH + step;
      msk[sub][step] = (t < TOK) ? (labels[(size_t)b * T + 1 + t] != -100) : 0;
    }
  }
  __syncthreads();

  const int sub = tid / NL, i = tid % NL;
  const int g = gbase + sub;
  const bool act = (sub < 7) && (g < nG);
  int len = 1;
  if (act) { const int c = g % C; len = min(LCH, TOK - (1 + c * LCH)); }

  float W[NL][NL];
#pragma unroll
  for (int k = 0; k < NL; ++k)
#pragma unroll
    for (int j = 0; j < NL; ++j) W[k][j] = __expf(tr2[k * NL + j]);

  float P[NL];
  {
    const int m0 = act ? msk[sub][0] : 0;
#pragma unroll
    for (int j = 0; j < NL; ++j)
      P[j] = m0 ? (tr2[i * NL + j] + e2[sub][0][j])
                : ((i == j) ? 0.f : -1e30f);
  }
  for (int step = 1; step < len; ++step) {
    const int mt = msk[sub][step];
    float mx = P[0];
#pragma unroll
    for (int k = 1; k < NL; ++k) mx = fmaxf(mx, P[k]);
    float E[NL];
#pragma unroll
    for (int k = 0; k < NL; ++k) E[k] = __expf(P[k] - mx);
    float Pn[NL];
#pragma unroll
    for (int j = 0; j < NL; ++j) {
      float s = 0.f;
#pragma unroll
      for (int k = 0; k < NL; ++k) s = fmaf(E[k], W[k][j], s);
      Pn[j] = mx + __logf(s) + e2[sub][step][j];
    }
#pragma unroll
    for (int j = 0; j < NL; ++j) P[j] = mt ? Pn[j] : P[j];
  }
  if (act) {
    float* dst = Pout + (size_t)g * 81 + i * NL;
#pragma unroll
    for (int j = 0; j < NL; ++j) dst[j] = P[j];
  }
}

// ---------------- Kernel 3: per-batch combine (num + den fold) --------------
__global__ __launch_bounds__(64) void combine_k(
    const float* __restrict__ e, const int* __restrict__ labels,
    const float* __restrict__ start_t, const float* __restrict__ end_t,
    const float* __restrict__ trans, const float* __restrict__ Pmat,
    float* __restrict__ llh, int B, int T, int C) {
  const int TOK = T - 2;
  const int b = blockIdx.x, lane = threadIdx.x;
  const float* eb = e + (size_t)b * TOK * NL;
  const int* lb = labels + (size_t)b * T + 1;

  const int g0r = lb[0];
  const int tg0 = (g0r == -100) ? 0 : g0r;
  float nsum = 0.f;
  int pack = -1;
  for (int t = 1 + lane; t < TOK; t += 64) {
    const int gr = lb[t], pr = lb[t - 1];
    if (gr != -100) {
      const int cur = gr;
      const int prev = (pr == -100) ? 0 : pr;
      nsum += trans[prev * NL + cur] + eb[t * NL + cur];
      pack = (t << 4) | cur;
    }
  }
#pragma unroll
  for (int off = 32; off; off >>= 1) {
    nsum += __shfl_xor(nsum, off);
    pack = max(pack, __shfl_xor(pack, off));
  }
  const int last = (pack < 0) ? tg0 : (pack & 15);
  const float num = start_t[tg0] + eb[tg0] + nsum + end_t[last];

  float alpha = (lane < NL) ? (start_t[lane] + eb[lane]) : -1e30f;
  for (int c = 0; c < C; ++c) {
    const float* Pc = Pmat + ((size_t)b * C + c) * 81;
    float col[NL];
#pragma unroll
    for (int i = 0; i < NL; ++i)
      col[i] = (lane < NL) ? Pc[i * NL + lane] : -1e30f;
    float s[NL];
    float mx = -1e30f;
#pragma unroll
    for (int i = 0; i < NL; ++i) {
      const float ai = __shfl(alpha, i);
      s[i] = ai + col[i];
      mx = fmaxf(mx, s[i]);
    }
    float sum = 0.f;
#pragma unroll
    for (int i = 0; i < NL; ++i) sum += __expf(s[i] - mx);
    const float nx = mx + __logf(sum);
    alpha = (lane < NL) ? nx : -1e30f;
  }
  const float v = (lane < NL) ? (alpha + end_t[lane]) : -1e30f;
  float mx = v;
#pragma unroll
  for (int off = 32; off; off >>= 1) mx = fmaxf(mx, __shfl_xor(mx, off));
  float sum = (lane < NL) ? __expf(v - mx) : 0.f;
#pragma unroll
  for (int off = 32; off; off >>= 1) sum += __shfl_xor(sum, off);
  const float den = mx + __logf(sum);
  if (lane == 0) llh[b] = num - den;
}

// ---------------- Kernel 4: -mean(llh) ----------------
__global__ __launch_bounds__(64) void reduce_k(const float* __restrict__ llh,
                                               float* __restrict__ out, int B) {
  float v = 0.f;
  for (int i = threadIdx.x; i < B; i += 64) v += llh[i];
#pragma unroll
  for (int off = 32; off; off >>= 1) v += __shfl_xor(v, off);
  if (threadIdx.x == 0) out[0] = -v / (float)B;
}

extern "C" void kernel_launch(void* const* d_in, const int* in_sizes, int n_in,
                              void* d_out, int out_size, void* d_ws,
                              size_t ws_size, hipStream_t stream) {
  const float* hs     = (const float*)d_in[0];
  const float* w      = (const float*)d_in[1];
  const float* bias   = (const float*)d_in[2];
  const float* st     = (const float*)d_in[3];
  const float* et     = (const float*)d_in[4];
  const float* tr     = (const float*)d_in[5];
  const int*   amask  = (const int*)d_in[6];
  const int*   labels = (const int*)d_in[7];

  const int T = 512;
  const int B = in_sizes[6] / T;
  const int TOK = T - 2;
  const int C = (TOK - 1 + LCH - 1) / LCH;

  float* e    = (float*)d_ws;                 // (B, TOK, 9)
  float* llh  = e + (size_t)B * TOK * NL;     // (B,)
  float* Pmat = llh + B;                      // (B*C, 81)

  const int nTok = B * TOK;
  const int nTile = (nTok + 15) / 16;         // 2040 for B=64
  mfma_k<<<nTile, 256, 0, stream>>>(hs, w, bias, amask, e, B);
  const int nG = B * C;
  chunk_k<<<(nG + 6) / 7, 64, 0, stream>>>(e, labels, tr, Pmat, B, T, C);
  combine_k<<<B, 64, 0, stream>>>(e, labels, st, et, tr, Pmat, llh, B, T, C);
  reduce_k<<<1, 64, 0, stream>>>(llh, (float*)d_out, B);
}